// Round 1
// baseline (742.104 us; speedup 1.0000x reference)
//
#include <hip/hip_runtime.h>
#include <hip/hip_bf16.h>

#define D_DIM 1024
#define NITER 20

typedef float f32x4 __attribute__((ext_vector_type(4)));
typedef __bf16 bf16x4 __attribute__((ext_vector_type(4)));
typedef __bf16 bf16x8 __attribute__((ext_vector_type(8)));

// ---- prep: M = exp(ls), Mt = M^T (tiled transpose through LDS) ----
__global__ __launch_bounds__(1024)
void prep_exp_transpose(const float* __restrict__ ls, float* __restrict__ Mm,
                        float* __restrict__ Mt) {
    __shared__ float tile[64][65];
    const int tx = threadIdx.x, ty = threadIdx.y;
    const int bx = blockIdx.x * 64, by = blockIdx.y * 64;
#pragma unroll
    for (int k = 0; k < 64; k += 16) {
        int r = by + ty + k, c = bx + tx;
        float v = expf(ls[r * D_DIM + c]);
        Mm[r * D_DIM + c] = v;
        tile[ty + k][tx] = v;
    }
    __syncthreads();
#pragma unroll
    for (int k = 0; k < 64; k += 16) {
        int r = bx + ty + k, c = by + tx;  // transposed block
        Mt[r * D_DIM + c] = tile[tx][ty + k];
    }
}

__global__ void init_u(float* u) { u[threadIdx.x] = 1.0f; }

// ---- y[i] = 1 / dot(A[i,:], x); one wave per row, 4 rows per block ----
__global__ __launch_bounds__(256)
void matvec_recip(const float* __restrict__ A, const float* __restrict__ x,
                  float* __restrict__ y) {
    const int wave = threadIdx.x >> 6, lane = threadIdx.x & 63;
    const int row = blockIdx.x * 4 + wave;
    const f32x4* Ar = (const f32x4*)(A + row * D_DIM);
    const f32x4* xr = (const f32x4*)x;
    float s = 0.f;
#pragma unroll
    for (int it = 0; it < 4; ++it) {
        f32x4 a = Ar[lane + it * 64];
        f32x4 b = xr[lane + it * 64];
        s += a.x * b.x + a.y * b.y + a.z * b.z + a.w * b.w;
    }
#pragma unroll
    for (int off = 32; off > 0; off >>= 1) s += __shfl_down(s, off, 64);
    if (lane == 0) y[row] = 1.0f / s;
}

// ---- P_bf16[i][j] = bf16(M[i][j] * r[i] * u[j])  (row-major; this is the
//      GEMM's "BT" operand: C[m][n] = sum_k A[m][k] * Bt[n][k]) ----
__global__ __launch_bounds__(256)
void finalize_P(const float* __restrict__ Mm, const float* __restrict__ r,
                const float* __restrict__ u, __bf16* __restrict__ P) {
    const int i = blockIdx.x;
    const int t = threadIdx.x;
    const float ri = r[i];
    f32x4 m = ((const f32x4*)(Mm + i * D_DIM))[t];
    f32x4 uu = ((const f32x4*)u)[t];
    bf16x4 o;
    o[0] = (__bf16)(m.x * ri * uu.x);
    o[1] = (__bf16)(m.y * ri * uu.y);
    o[2] = (__bf16)(m.z * ri * uu.z);
    o[3] = (__bf16)(m.w * ri * uu.w);
    ((bf16x4*)(P + i * D_DIM))[t] = o;
}

// ---- GEMM: C (MxN, f32) = A (MxK, f32, cast->bf16) * Bt (NxK, bf16)^T ----
#define BM 128
#define BN 128
#define BK 32

__global__ __launch_bounds__(256)
void gemm_a32_bt16(const float* __restrict__ A, const __bf16* __restrict__ Bt,
                   float* __restrict__ C, int Msz, int Nsz, int Ksz) {
    __shared__ __bf16 As[BM * BK];  // [m][k], stride 32
    __shared__ __bf16 Bs[BN * BK];  // [n][k], stride 32 (global_load_lds needs contiguous)
    const int tid = threadIdx.x;
    const int wave = tid >> 6, lane = tid & 63;
    const int wm = wave >> 1, wn = wave & 1;   // 2x2 wave grid, 64x64 per wave
    const int quad = lane >> 4, l16 = lane & 15;
    const int m0 = blockIdx.y * BM, n0 = blockIdx.x * BN;

    f32x4 acc[4][4] = {};

    for (int k0 = 0; k0 < Ksz; k0 += BK) {
        __syncthreads();  // previous iteration's LDS readers done
        // stage A: 128x32 fp32 -> bf16 (1024 float4 loads, 4/thread)
#pragma unroll
        for (int it = 0; it < 4; ++it) {
            int idx = tid + it * 256;
            int row = idx >> 3, kq = idx & 7;
            f32x4 v = *(const f32x4*)(A + (size_t)(m0 + row) * Ksz + k0 + kq * 4);
            bf16x4 b;
            b[0] = (__bf16)v.x; b[1] = (__bf16)v.y;
            b[2] = (__bf16)v.z; b[3] = (__bf16)v.w;
            *(bf16x4*)(&As[row * BK + kq * 4]) = b;
        }
        // stage B: async global->LDS, 16B/lane, wave-uniform LDS base
#pragma unroll
        for (int q = 0; q < 2; ++q) {
            int t8 = wave * 2 + q;                     // 0..7, 16 n-rows each
            int nrow = t8 * 16 + (lane >> 2);
            const __bf16* g = Bt + (size_t)(n0 + nrow) * Ksz + k0 + (lane & 3) * 8;
            __bf16* l = Bs + t8 * 512;                 // 1024 B per issue
            __builtin_amdgcn_global_load_lds(
                (const __attribute__((address_space(1))) void*)g,
                (__attribute__((address_space(3))) void*)l, 16, 0, 0);
        }
        __syncthreads();  // compiler emits vmcnt(0)+lgkmcnt(0) drain here

        bf16x8 af[4], bfr[4];
#pragma unroll
        for (int a = 0; a < 4; ++a)
            af[a] = *(const bf16x8*)(&As[(wm * 64 + a * 16 + l16) * BK + quad * 8]);
#pragma unroll
        for (int b = 0; b < 4; ++b)
            bfr[b] = *(const bf16x8*)(&Bs[(wn * 64 + b * 16 + l16) * BK + quad * 8]);
#pragma unroll
        for (int a = 0; a < 4; ++a)
#pragma unroll
            for (int b = 0; b < 4; ++b)
                acc[a][b] = __builtin_amdgcn_mfma_f32_16x16x32_bf16(
                    af[a], bfr[b], acc[a][b], 0, 0, 0);
    }

    // epilogue: C/D layout col = lane&15, row = quad*4 + reg
#pragma unroll
    for (int a = 0; a < 4; ++a) {
        int mg = m0 + wm * 64 + a * 16 + quad * 4;
#pragma unroll
        for (int b = 0; b < 4; ++b) {
            int ng = n0 + wn * 64 + b * 16 + l16;
#pragma unroll
            for (int v = 0; v < 4; ++v)
                C[(size_t)(mg + v) * Nsz + ng] = acc[a][b][v];
        }
    }
}

extern "C" void kernel_launch(void* const* d_in, const int* in_sizes, int n_in,
                              void* d_out, int out_size, void* d_ws, size_t ws_size,
                              hipStream_t stream) {
    const float* emb = (const float*)d_in[0];   // (B, 1024) f32
    const float* ls  = (const float*)d_in[1];   // (1024, 1024) f32
    float* out = (float*)d_out;                 // (B, 1024) f32
    char* ws = (char*)d_ws;

    float* Mm  = (float*)ws;                         // 4 MB
    float* Mt  = (float*)(ws + (4u << 20));          // 4 MB
    float* r   = (float*)(ws + (8u << 20));          // 4 KB
    float* u   = (float*)(ws + (8u << 20) + 4096);   // 4 KB
    __bf16* P  = (__bf16*)(ws + (8u << 20) + 8192);  // 2 MB

    const int B = in_sizes[0] / D_DIM;  // 65536

    prep_exp_transpose<<<dim3(16, 16), dim3(64, 16), 0, stream>>>(ls, Mm, Mt);
    init_u<<<1, D_DIM, 0, stream>>>(u);
    for (int it = 0; it < NITER; ++it) {
        matvec_recip<<<D_DIM / 4, 256, 0, stream>>>(Mm, u, r);   // r = 1/(M u)
        matvec_recip<<<D_DIM / 4, 256, 0, stream>>>(Mt, r, u);   // u = 1/(M^T r)
    }
    finalize_P<<<D_DIM, 256, 0, stream>>>(Mm, r, u, P);
    gemm_a32_bt16<<<dim3(D_DIM / BN, B / BM), 256, 0, stream>>>(
        emb, P, out, B, D_DIM, D_DIM);
}